// Round 17
// baseline (376.750 us; speedup 1.0000x reference)
//
#include <hip/hip_runtime.h>
#include <hip/hip_bf16.h>
#include <math.h>

typedef __hip_bfloat16 bf16;
typedef __attribute__((ext_vector_type(8))) short short8;
typedef __attribute__((ext_vector_type(4))) short short4v;
typedef __attribute__((ext_vector_type(4))) float f32x4;
typedef __attribute__((ext_vector_type(2))) int int2v;

#define MFMA16(a, b, c) __builtin_amdgcn_mfma_f32_16x16x32_bf16((a), (b), (c), 0, 0, 0)

typedef const __attribute__((address_space(1))) void GVOID;
typedef __attribute__((address_space(3))) void LVOID;

__device__ __forceinline__ float b2f(short s) {
    union { unsigned u; float f; } v;
    v.u = ((unsigned)(unsigned short)s) << 16;
    return v.f;
}
__device__ __forceinline__ short f2b(float f) {
    union { float f; unsigned u; } v;
    v.f = f;
    unsigned r = v.u + 0x7fffu + ((v.u >> 16) & 1u);
    return (short)(r >> 16);
}
__device__ __forceinline__ unsigned packbf2(float a, float b) {
    float2 t; t.x = a; t.y = b;
    __hip_bfloat162 h = __float22bfloat162_rn(t);
    union { __hip_bfloat162 h; unsigned u; } cv; cv.h = h;
    return cv.u;
}
__device__ __forceinline__ short bf2s(float x) {
    __hip_bfloat16 h = __float2bfloat16(x);
    union { __hip_bfloat16 h; short s; } cv; cv.h = h;
    return cv.s;
}

#if __has_builtin(__builtin_amdgcn_permlane32_swap)
__device__ __forceinline__ float addx32(float x) {
    union { float f; int i; } c; c.f = x;
    int2v r = __builtin_amdgcn_permlane32_swap(c.i, c.i, false, false);
    union { int i; float f; } a, b; a.i = r[0]; b.i = r[1];
    return a.f + b.f;
}
__device__ __forceinline__ float maxx32(float x) {
    union { float f; int i; } c; c.f = x;
    int2v r = __builtin_amdgcn_permlane32_swap(c.i, c.i, false, false);
    union { int i; float f; } a, b; a.i = r[0]; b.i = r[1];
    return fmaxf(a.f, b.f);
}
#else
__device__ __forceinline__ float addx32(float x) { return x + __shfl_xor(x, 32); }
__device__ __forceinline__ float maxx32(float x) { return fmaxf(x, __shfl_xor(x, 32)); }
#endif

// ---------------------------------------------------------------------------
// prep: block 0 = dtype sniff + small-vector canon; blocks 1..384 = RoPE tables.
// ---------------------------------------------------------------------------
__global__ __launch_bounds__(256) void prep_kernel(
    const unsigned* __restrict__ X,
    const void* __restrict__ bq, const void* __restrict__ bk,
    const void* __restrict__ bv, const void* __restrict__ bo,
    const void* __restrict__ qw, const void* __restrict__ kw,
    int* __restrict__ flag, float* __restrict__ biasqkv, float* __restrict__ boc,
    float* __restrict__ qwc, float* __restrict__ kwc,
    float* __restrict__ cosT, float* __restrict__ sinT)
{
    const int tid = threadIdx.x;
    if (blockIdx.x == 0) {
        __shared__ int cnt;
        if (tid == 0) cnt = 0;
        __syncthreads();
        unsigned w = X[tid];
        unsigned e = (w >> 7) & 0xFFu;
        if (e > 140u) atomicAdd(&cnt, 1);
        __syncthreads();
        const int f = (cnt >= 16) ? 1 : 0;
        if (tid == 0) *flag = f;
        for (int i = tid; i < 6336; i += 256) {
            const void* src; float* dst; int j;
            if (i < 4608) {
                int m = i / 1536; j = i - m * 1536;
                src = (m == 0) ? bq : (m == 1) ? bk : bv; dst = biasqkv + i;
            } else if (i < 6144) { j = i - 4608; src = bo; dst = boc + j; }
            else if (i < 6240)   { j = i - 6144; src = qw; dst = qwc + j; }
            else                 { j = i - 6240; src = kw; dst = kwc + j; }
            *dst = f ? ((const float*)src)[j] : b2f(((const short*)src)[j]);
        }
    } else {
        int idx = (blockIdx.x - 1) * 256 + tid;
        if (idx >= 1024 * 96) return;
        int p = idx / 96;
        int d = idx - p * 96;
        int r = p >> 5, c = p & 31;
        int inRow = (d < 48);
        int dd = inRow ? d : d - 48;
        float pos = inRow ? (float)r : (float)c;
        float ex = -(float)(dd & ~1) / 48.0f;
        float f = powf(10000.0f, ex);
        float ang = pos * f;
        cosT[idx] = cosf(ang);
        sinT[idx] = sinf(ang);
    }
}

// ---------------------------------------------------------------------------
// canon_all: X (6144 blocks) + 4 weight matrices (1152 blocks each).
// ---------------------------------------------------------------------------
__device__ __forceinline__ void canon8(const void* src, short* dst, int i, int f) {
    short8 o;
    if (f) {
        const float* s = (const float*)src + (size_t)i * 8;
#pragma unroll
        for (int j = 0; j < 8; ++j) o[j] = f2b(s[j]);
    } else {
        o = ((const short8*)src)[i];
    }
    ((short8*)dst)[i] = o;
}

__global__ __launch_bounds__(256) void canon_all_kernel(
    const void* __restrict__ X,
    const void* __restrict__ s0, const void* __restrict__ s1,
    const void* __restrict__ s2, const void* __restrict__ s3,
    short* __restrict__ dX,
    short* __restrict__ d0, short* __restrict__ d1,
    short* __restrict__ d2, short* __restrict__ d3,
    const int* __restrict__ flag)
{
    const int f = *flag;
    const int bid = blockIdx.x;
    if (bid < 6144) {
        canon8(X, dX, bid * 256 + threadIdx.x, f);
    } else {
        const int wb = bid - 6144;
        const int m = wb / 1152;
        const int i = (wb - m * 1152) * 256 + threadIdx.x;
        const void* src = (m == 0) ? s0 : (m == 1) ? s1 : (m == 2) ? s2 : s3;
        short* dst = (m == 0) ? d0 : (m == 1) ? d1 : (m == 2) ? d2 : d3;
        canon8(src, dst, i, f);
    }
}

// ---------------------------------------------------------------------------
// 128x128 NT GEMM, BK=64, dbuf (64KB -> 2 blocks/CU), conflicts 0, 780+ TF.
// L2-band mapping (r16, +7us): each XCD owns a fixed 8-row mb band, nb-major
// walk. FETCH 289->117MB measured. Requires 64 mb tiles. mat = nb/12.
// ---------------------------------------------------------------------------
__global__ __launch_bounds__(256) void gemm128_kernel(
    const bf16* __restrict__ A, const bf16* __restrict__ Bw,
    const float* __restrict__ bias,
    bf16* __restrict__ O0, bf16* __restrict__ O1, bf16* __restrict__ O2,
    int K, const int* __restrict__ outFlag)
{
    __shared__ __align__(16) short As[2][128 * 64];
    __shared__ __align__(16) short Bs[2][128 * 64];

    const int tid = threadIdx.x;
    const int lane = tid & 63, w = tid >> 6;
    const int wr = w >> 1, wc = w & 1;
    const int li = lane & 15, lg = lane >> 4;

    const int pp = blockIdx.y * gridDim.x + blockIdx.x;
    const int xcd = pp & 7;
    const int idx = pp >> 3;
    const int mb = xcd * 8 + (idx & 7);
    const int nb = idx >> 3;
    const long mBase = (long)mb * 128;
    const long nGlob = (long)nb * 128;

    const bf16* aSrc[4]; const bf16* bSrc[4]; int ldsOff[4];
#pragma unroll
    for (int u = 0; u < 4; ++u) {
        const int L = u * 4096 + tid * 16;
        const int S = L ^ (((L >> 7) & 7) << 4);
        const int srow = S >> 7;
        const int scol = (S & 127) >> 1;
        aSrc[u] = A + (mBase + srow) * K + scol;
        bSrc[u] = Bw + (nGlob + srow) * K + scol;
        ldsOff[u] = L >> 1;
    }
    const int rxor = (li & 7) << 4;
    int kidx[2];
#pragma unroll
    for (int ks = 0; ks < 2; ++ks)
        kidx[ks] = ((ks * 64 + lg * 16) ^ rxor) >> 1;

    f32x4 acc[4][4] = {};
    const int NT = K >> 6;

    auto stage = [&](int tt, int bb) {
        const long kc = (long)tt * 64;
#pragma unroll
        for (int u = 0; u < 4; ++u)
            __builtin_amdgcn_global_load_lds((GVOID*)(aSrc[u] + kc),
                                             (LVOID*)&As[bb][ldsOff[u]], 16, 0, 0);
#pragma unroll
        for (int u = 0; u < 4; ++u)
            __builtin_amdgcn_global_load_lds((GVOID*)(bSrc[u] + kc),
                                             (LVOID*)&Bs[bb][ldsOff[u]], 16, 0, 0);
    };

    stage(0, 0);
    asm volatile("s_waitcnt vmcnt(0)" ::: "memory");
    __builtin_amdgcn_s_barrier();
    asm volatile("" ::: "memory");

    for (int t = 0; t < NT; ++t) {
        const int cb = t & 1;
        if (t + 1 < NT) stage(t + 1, cb ^ 1);
        const short* Ab = &As[cb][0];
        const short* Bb = &Bs[cb][0];
#pragma unroll
        for (int ks = 0; ks < 2; ++ks) {
            short8 fa[4], fb[4];
#pragma unroll
            for (int m = 0; m < 4; ++m)
                fa[m] = *(const short8*)(Ab + (wr * 64 + m * 16 + li) * 64 + kidx[ks]);
#pragma unroll
            for (int n = 0; n < 4; ++n)
                fb[n] = *(const short8*)(Bb + (wc * 64 + n * 16 + li) * 64 + kidx[ks]);
            __builtin_amdgcn_sched_barrier(0);
            __builtin_amdgcn_s_setprio(1);
#pragma unroll
            for (int m = 0; m < 4; ++m)
#pragma unroll
                for (int n = 0; n < 4; ++n)
                    acc[m][n] = MFMA16(fa[m], fb[n], acc[m][n]);
            __builtin_amdgcn_s_setprio(0);
            __builtin_amdgcn_sched_barrier(0);
        }
        asm volatile("s_waitcnt vmcnt(0)" ::: "memory");
        __builtin_amdgcn_s_barrier();
        asm volatile("" ::: "memory");
    }

    const int f32out = outFlag ? *outFlag : 0;
    const int mat = nb / 12;
    const long colBase = nGlob - (long)mat * 1536;
    bf16* Ob = (mat == 0) ? O0 : (mat == 1) ? O1 : O2;
    if (f32out) {
        float* Cf = (float*)Ob;
#pragma unroll
        for (int n = 0; n < 4; ++n) {
            const long col = colBase + wc * 64 + n * 16 + li;
            const float bv = bias[nGlob + wc * 64 + n * 16 + li];
#pragma unroll
            for (int m = 0; m < 4; ++m) {
                const long row = mBase + wr * 64 + m * 16 + lg * 4;
#pragma unroll
                for (int i = 0; i < 4; ++i)
                    Cf[(row + i) * 1536 + col] = acc[m][n][i] + bv;
            }
        }
    } else {
#pragma unroll
        for (int n = 0; n < 4; ++n) {
            const long col = colBase + wc * 64 + n * 16 + li;
            const float bv = bias[nGlob + wc * 64 + n * 16 + li];
#pragma unroll
            for (int m = 0; m < 4; ++m) {
                const long row = mBase + wr * 64 + m * 16 + lg * 4;
#pragma unroll
                for (int i = 0; i < 4; ++i)
                    Ob[(row + i) * 1536 + col] = __float2bfloat16(acc[m][n][i] + bv);
            }
        }
    }
}

// ---------------------------------------------------------------------------
// Fused per-head RMSNorm + RoPE, in place; y=0 -> Q (qscale), y=1 -> K.
// ---------------------------------------------------------------------------
__global__ __launch_bounds__(256) void norm_rope2_kernel(
    bf16* __restrict__ Qb, bf16* __restrict__ Kb,
    const float* __restrict__ qwc, const float* __restrict__ kwc,
    const float* __restrict__ cosT, const float* __restrict__ sinT,
    float qscale)
{
    bf16* T = blockIdx.y ? Kb : Qb;
    const float* wgt = blockIdx.y ? kwc : qwc;
    const float scale = blockIdx.y ? 1.0f : qscale;

    const int row = blockIdx.x * 256 + threadIdx.x;
    const int tok = row >> 4;
    const int h = row & 15;
    const int spos = tok & 1023;
    bf16* p = T + (size_t)tok * 1536 + h * 96;

    float x[96];
#pragma unroll
    for (int v = 0; v < 12; ++v) {
        short8 t = *(const short8*)(p + v * 8);
#pragma unroll
        for (int j = 0; j < 8; ++j) x[v * 8 + j] = b2f(t[j]);
    }
    float ss = 0.f;
#pragma unroll
    for (int d = 0; d < 96; ++d) ss += x[d] * x[d];
    const float rn = scale / sqrtf(ss * (1.0f / 96.0f) + 1e-6f);

    const float* cr = cosT + spos * 96;
    const float* sr = sinT + spos * 96;

#pragma unroll
    for (int v = 0; v < 12; ++v) {
        short8 o;
#pragma unroll
        for (int j = 0; j < 8; j += 2) {
            const int d = v * 8 + j;
            const float x0 = x[d] * rn * wgt[d];
            const float x1 = x[d + 1] * rn * wgt[d + 1];
            o[j]     = f2b(x0 * cr[d] - x1 * sr[d]);
            o[j + 1] = f2b(x1 * cr[d + 1] + x0 * sr[d + 1]);
        }
        *(short8*)(p + v * 8) = o;
    }
}

// ---------------------------------------------------------------------------
// Flash attention v7: permuted-key QK fragments make P LANE-LOCAL for PV.
// MFMA16 input A-row r = output row r, so loading K fragment rows as
//   row(x) = kt*32 + 8*(x>>2) + 4*h + (x&3)
// puts key kt*32+8lg+4h+i in output lane (li,lg) reg i — exactly the PV
// B-operand window (q=li, k=lg*8..+7). Softmax unchanged (order-agnostic,
// same 64-key union). Pl LDS + its write/read round-trip DELETED:
// LDS 48KB -> 3 blocks/CU (was 2) and the softmax->PV chain is pure-register.
// ---------------------------------------------------------------------------
__global__ __launch_bounds__(512, 2) void attn_kernel(
    const bf16* __restrict__ Q, const bf16* __restrict__ K,
    const bf16* __restrict__ V, bf16* __restrict__ O)
{
    __shared__ __align__(16) short Ks[2][64 * 96];
    __shared__ __align__(16) short Vt[2][96 * 64];

    const int tid = threadIdx.x;
    const int l = tid & 63, w = tid >> 6;
    const int li = l & 15, lg = l >> 4;

    const int p = blockIdx.x;
    const int lb = (p & 7) * 128 + (p >> 3);
    const int qt = lb & 7;
    const int bh = lb >> 3;
    const int b = bh >> 4, h = bh & 15;
    const size_t tokBase = (size_t)b * 1024;

    short8 aq[3];
    {
        const bf16* qp = Q + (tokBase + qt * 128 + w * 16 + li) * 1536 + h * 96;
#pragma unroll
        for (int kk = 0; kk < 3; ++kk)
            aq[kk] = *(const short8*)(qp + kk * 32 + lg * 8);
    }

    float m_r = -1e30f, l_r = 0.f;
    f32x4 o[6] = {};

    const bool kst = (w >= 4);
    int kr[3], km[3], kso[3];
#pragma unroll
    for (int u = 0; u < 3; ++u) {
        const int c = (tid - 256) + 256 * u;
        const int crr = c / 12;
        kr[u] = crr;
        km[u] = (c - crr * 12) * 8;
        kso[u] = (crr * 96 + km[u]) ^ ((crr & 7) << 3);
    }
    const int t2 = tid >> 3;
    const int dh = tid & 7;
    const bf16* vbase = V + (tokBase + 2 * t2) * 1536 + h * 96 + dh * 12;

    // permuted QK fragment rows: rowbase = 8*(li>>2) + (li&3); row = kt*32+4h+rowbase
    const int rowbase = ((li >> 2) << 3) + (li & 3);
    const int colb = lg * 8;
    int frow[2][2];   // frow[kt][h] = row*96
    int fswz[2];      // swz depends only on h: (4h + (li&3))<<3
#pragma unroll
    for (int kt = 0; kt < 2; ++kt)
#pragma unroll
        for (int hh = 0; hh < 2; ++hh)
            frow[kt][hh] = (kt * 32 + 4 * hh + rowbase) * 96;
#pragma unroll
    for (int hh = 0; hh < 2; ++hh)
        fswz[hh] = (4 * hh + (li & 3)) << 3;

    const int vswz = ((li >> 1) & 7) << 3;

    short8 kreg[3];
    short4v vr0[3], vr1[3];
    auto loadT = [&](int tt) {
        if (kst) {
#pragma unroll
            for (int u = 0; u < 3; ++u)
                kreg[u] = *(const short8*)(K + (tokBase + tt + kr[u]) * 1536 + h * 96 + km[u]);
        } else {
            const bf16* vp = vbase + (size_t)tt * 1536;
#pragma unroll
            for (int u = 0; u < 3; ++u) {
                vr0[u] = *(const short4v*)(vp + u * 4);
                vr1[u] = *(const short4v*)(vp + 1536 + u * 4);
            }
        }
    };
    auto writeT = [&](int bb) {
        if (kst) {
#pragma unroll
            for (int u = 0; u < 3; ++u)
                *(short8*)&Ks[bb][kso[u]] = kreg[u];
        } else {
            unsigned* Vt32 = (unsigned*)&Vt[bb][0];
#pragma unroll
            for (int u = 0; u < 3; ++u)
#pragma unroll
                for (int j = 0; j < 4; ++j) {
                    const int d = dh * 12 + u * 4 + j;
                    const unsigned pk = ((unsigned)(unsigned short)vr0[u][j]) |
                                        (((unsigned)(unsigned short)vr1[u][j]) << 16);
                    Vt32[(d * 32 + t2) ^ (((d >> 1) & 7) << 2)] = pk;
                }
        }
    };

    loadT(0);
    writeT(0);
    loadT(64);
    __syncthreads();

    for (int t = 0; t < 16; ++t) {
        const int cb = t & 1;

        // QK^T with permuted key rows: s4[2kt+h][i] = S^T[key=kt*32+8lg+4h+i][q=li]
        f32x4 s4[4] = {};
#pragma unroll
        for (int kk = 0; kk < 3; ++kk) {
            const int ck = kk * 32 + colb;
#pragma unroll
            for (int kt = 0; kt < 2; ++kt)
#pragma unroll
                for (int hh = 0; hh < 2; ++hh) {
                    short8 fk = *(const short8*)&Ks[cb][(frow[kt][hh] + ck) ^ fswz[hh]];
                    s4[kt * 2 + hh] = MFMA16(fk, aq[kk], s4[kt * 2 + hh]);
                }
        }

        if (t < 15) writeT(cb ^ 1);
        if (t < 14) loadT((t + 2) * 64);

        // softmax (order-agnostic over the 64-key union) -> P packed in regs
        unsigned pdw[4][2];
        {
            float mk[4];
#pragma unroll
            for (int kn = 0; kn < 4; ++kn)
                mk[kn] = fmaxf(fmaxf(s4[kn][0], s4[kn][1]),
                               fmaxf(s4[kn][2], s4[kn][3]));
            float pm = fmaxf(fmaxf(mk[0], mk[1]), fmaxf(mk[2], mk[3]));
            pm = fmaxf(pm, __shfl_xor(pm, 16));
            pm = maxx32(pm);

            float alpha = 1.0f;
            const bool need = (pm > m_r + 8.0f);
            if (need) { alpha = exp2f(m_r - pm); m_r = pm; }
            const float mn = m_r;

            float rs = 0.f;
#pragma unroll
            for (int kn = 0; kn < 4; ++kn) {
                float p0 = exp2f(s4[kn][0] - mn);
                float p1 = exp2f(s4[kn][1] - mn);
                float p2 = exp2f(s4[kn][2] - mn);
                float p3 = exp2f(s4[kn][3] - mn);
                rs += (p0 + p1) + (p2 + p3);
                pdw[kn][0] = packbf2(p0, p1);
                pdw[kn][1] = packbf2(p2, p3);
            }
            rs += __shfl_xor(rs, 16);
            rs = addx32(rs);
            l_r = l_r * alpha + rs;
            if (need) {
#pragma unroll
                for (int dn = 0; dn < 6; ++dn)
#pragma unroll
                    for (int i = 0; i < 4; ++i) o[dn][i] *= alpha;
            }
        }

        // PV: pa is lane-local (keys kt*32+8lg..+7 = [s4[2kt], s4[2kt+1]])
#pragma unroll
        for (int kt = 0; kt < 2; ++kt) {
            union { unsigned u[4]; short8 s; } pa;
            pa.u[0] = pdw[kt * 2][0];
            pa.u[1] = pdw[kt * 2][1];
            pa.u[2] = pdw[kt * 2 + 1][0];
            pa.u[3] = pdw[kt * 2 + 1][1];
#pragma unroll
            for (int dn = 0; dn < 6; ++dn) {
                short8 fv = *(const short8*)&Vt[cb][((dn * 16 + li) * 64 + kt * 32 + lg * 8) ^ vswz];
                o[dn] = MFMA16(fv, pa.s, o[dn]);
            }
        }

        __syncthreads();
    }

    {
        const float inv = 1.0f / l_r;
        const size_t row = tokBase + qt * 128 + w * 16 + li;
#pragma unroll
        for (int dn = 0; dn < 6; ++dn) {
            short4v ov;
#pragma unroll
            for (int i = 0; i < 4; ++i) ov[i] = bf2s(o[dn][i] * inv);
            *(short4v*)&O[row * 1536 + h * 96 + dn * 16 + lg * 4] = ov;
        }
    }
}

// ---------------------------------------------------------------------------
extern "C" void kernel_launch(void* const* d_in, const int* in_sizes, int n_in,
                              void* d_out, int out_size, void* d_ws, size_t ws_size,
                              hipStream_t stream) {
    const void* X  = d_in[0];
    const void* Wq = d_in[1];
    const void* bq = d_in[2];
    const void* Wk = d_in[3];
    const void* bk = d_in[4];
    const void* Wv = d_in[5];
    const void* bv = d_in[6];
    const void* qw = d_in[7];
    const void* kw = d_in[8];
    const void* Wo = d_in[9];
    const void* bo = d_in[10];

    char* ws = (char*)d_ws;
    size_t off = 0;
    int* flag = (int*)ws;                      off += 256;
    float* cosT = (float*)(ws + off);          off += 1024 * 96 * 4;
    float* sinT = (float*)(ws + off);          off += 1024 * 96 * 4;
    float* biasqkv = (float*)(ws + off);       off += 4608 * 4;
    float* boc  = (float*)(ws + off);          off += 1536 * 4;
    float* qwc  = (float*)(ws + off);          off += 128 * 4;
    float* kwc  = (float*)(ws + off);          off += 128 * 4;
    off = (off + 255) & ~(size_t)255;
    bf16* Wc  = (bf16*)(ws + off);             off += (size_t)4608 * 1536 * 2;
    bf16* Woc = (bf16*)(ws + off);             off += (size_t)1536 * 1536 * 2;
    bf16* Xc  = (bf16*)(ws + off);             off += (size_t)8192 * 1536 * 2;  // reused as AO
    bf16* Qb  = (bf16*)(ws + off);             off += (size_t)8192 * 1536 * 2;
    bf16* Kb  = (bf16*)(ws + off);             off += (size_t)8192 * 1536 * 2;
    bf16* Vb  = (bf16*)(ws + off);             off += (size_t)8192 * 1536 * 2;
    bf16* AO  = Xc;

    prep_kernel<<<385, 256, 0, stream>>>((const unsigned*)X, bq, bk, bv, bo, qw, kw,
                                         flag, biasqkv, boc, qwc, kwc, cosT, sinT);

    canon_all_kernel<<<10752, 256, 0, stream>>>(
        X, Wq, Wk, Wv, Wo,
        (short*)Xc, (short*)Wc, (short*)(Wc + (size_t)1536 * 1536),
        (short*)(Wc + (size_t)2 * 1536 * 1536), (short*)Woc, flag);

    // fused QKV projection: [8192,4608] = Xc @ Wc^T + biasqkv -> Qb|Kb|Vb
    gemm128_kernel<<<dim3(36, 64), 256, 0, stream>>>(
        Xc, Wc, biasqkv, Qb, Kb, Vb, 1536, nullptr);

    const float qscale = (float)(0.10206207261596577 * 1.4426950408889634);
    norm_rope2_kernel<<<dim3(512, 2), 256, 0, stream>>>(Qb, Kb, qwc, kwc, cosT, sinT, qscale);

    attn_kernel<<<1024, 512, 0, stream>>>(Qb, Kb, Vb, AO);

    gemm128_kernel<<<dim3(12, 64), 256, 0, stream>>>(
        AO, Woc, boc, (bf16*)d_out, (bf16*)d_out, (bf16*)d_out, 1536, flag);
}

// Round 18
// 374.421 us; speedup vs baseline: 1.0062x; 1.0062x over previous
//
#include <hip/hip_runtime.h>
#include <hip/hip_bf16.h>
#include <math.h>

typedef __hip_bfloat16 bf16;
typedef __attribute__((ext_vector_type(8))) short short8;
typedef __attribute__((ext_vector_type(4))) short short4v;
typedef __attribute__((ext_vector_type(4))) float f32x4;
typedef __attribute__((ext_vector_type(2))) int int2v;

#define MFMA16(a, b, c) __builtin_amdgcn_mfma_f32_16x16x32_bf16((a), (b), (c), 0, 0, 0)

typedef const __attribute__((address_space(1))) void GVOID;
typedef __attribute__((address_space(3))) void LVOID;

__device__ __forceinline__ float b2f(short s) {
    union { unsigned u; float f; } v;
    v.u = ((unsigned)(unsigned short)s) << 16;
    return v.f;
}
__device__ __forceinline__ short f2b(float f) {
    union { float f; unsigned u; } v;
    v.f = f;
    unsigned r = v.u + 0x7fffu + ((v.u >> 16) & 1u);
    return (short)(r >> 16);
}
__device__ __forceinline__ unsigned packbf2(float a, float b) {
    float2 t; t.x = a; t.y = b;
    __hip_bfloat162 h = __float22bfloat162_rn(t);
    union { __hip_bfloat162 h; unsigned u; } cv; cv.h = h;
    return cv.u;
}
__device__ __forceinline__ short bf2s(float x) {
    __hip_bfloat16 h = __float2bfloat16(x);
    union { __hip_bfloat16 h; short s; } cv; cv.h = h;
    return cv.s;
}

// Cross-lane reduces on the VALU pipe (no DS-latency hop).
#if __has_builtin(__builtin_amdgcn_permlane32_swap)
__device__ __forceinline__ float addx32(float x) {
    union { float f; int i; } c; c.f = x;
    int2v r = __builtin_amdgcn_permlane32_swap(c.i, c.i, false, false);
    union { int i; float f; } a, b; a.i = r[0]; b.i = r[1];
    return a.f + b.f;
}
__device__ __forceinline__ float maxx32(float x) {
    union { float f; int i; } c; c.f = x;
    int2v r = __builtin_amdgcn_permlane32_swap(c.i, c.i, false, false);
    union { int i; float f; } a, b; a.i = r[0]; b.i = r[1];
    return fmaxf(a.f, b.f);
}
#else
__device__ __forceinline__ float addx32(float x) { return x + __shfl_xor(x, 32); }
__device__ __forceinline__ float maxx32(float x) { return fmaxf(x, __shfl_xor(x, 32)); }
#endif

#if __has_builtin(__builtin_amdgcn_permlane16_swap)
__device__ __forceinline__ float addx16(float x) {
    union { float f; int i; } c; c.f = x;
    int2v r = __builtin_amdgcn_permlane16_swap(c.i, c.i, false, false);
    union { int i; float f; } a, b; a.i = r[0]; b.i = r[1];
    return a.f + b.f;
}
__device__ __forceinline__ float maxx16(float x) {
    union { float f; int i; } c; c.f = x;
    int2v r = __builtin_amdgcn_permlane16_swap(c.i, c.i, false, false);
    union { int i; float f; } a, b; a.i = r[0]; b.i = r[1];
    return fmaxf(a.f, b.f);
}
#else
__device__ __forceinline__ float addx16(float x) { return x + __shfl_xor(x, 16); }
__device__ __forceinline__ float maxx16(float x) { return fmaxf(x, __shfl_xor(x, 16)); }
#endif

// ---------------------------------------------------------------------------
// prep: block 0 = dtype sniff + small-vector canon; blocks 1..384 = RoPE tables.
// ---------------------------------------------------------------------------
__global__ __launch_bounds__(256) void prep_kernel(
    const unsigned* __restrict__ X,
    const void* __restrict__ bq, const void* __restrict__ bk,
    const void* __restrict__ bv, const void* __restrict__ bo,
    const void* __restrict__ qw, const void* __restrict__ kw,
    int* __restrict__ flag, float* __restrict__ biasqkv, float* __restrict__ boc,
    float* __restrict__ qwc, float* __restrict__ kwc,
    float* __restrict__ cosT, float* __restrict__ sinT)
{
    const int tid = threadIdx.x;
    if (blockIdx.x == 0) {
        __shared__ int cnt;
        if (tid == 0) cnt = 0;
        __syncthreads();
        unsigned w = X[tid];
        unsigned e = (w >> 7) & 0xFFu;
        if (e > 140u) atomicAdd(&cnt, 1);
        __syncthreads();
        const int f = (cnt >= 16) ? 1 : 0;
        if (tid == 0) *flag = f;
        for (int i = tid; i < 6336; i += 256) {
            const void* src; float* dst; int j;
            if (i < 4608) {
                int m = i / 1536; j = i - m * 1536;
                src = (m == 0) ? bq : (m == 1) ? bk : bv; dst = biasqkv + i;
            } else if (i < 6144) { j = i - 4608; src = bo; dst = boc + j; }
            else if (i < 6240)   { j = i - 6144; src = qw; dst = qwc + j; }
            else                 { j = i - 6240; src = kw; dst = kwc + j; }
            *dst = f ? ((const float*)src)[j] : b2f(((const short*)src)[j]);
        }
    } else {
        int idx = (blockIdx.x - 1) * 256 + tid;
        if (idx >= 1024 * 96) return;
        int p = idx / 96;
        int d = idx - p * 96;
        int r = p >> 5, c = p & 31;
        int inRow = (d < 48);
        int dd = inRow ? d : d - 48;
        float pos = inRow ? (float)r : (float)c;
        float ex = -(float)(dd & ~1) / 48.0f;
        float f = powf(10000.0f, ex);
        float ang = pos * f;
        cosT[idx] = cosf(ang);
        sinT[idx] = sinf(ang);
    }
}

// ---------------------------------------------------------------------------
// canon_all: X (6144 blocks) + 4 weight matrices (1152 blocks each).
// ---------------------------------------------------------------------------
__device__ __forceinline__ void canon8(const void* src, short* dst, int i, int f) {
    short8 o;
    if (f) {
        const float* s = (const float*)src + (size_t)i * 8;
#pragma unroll
        for (int j = 0; j < 8; ++j) o[j] = f2b(s[j]);
    } else {
        o = ((const short8*)src)[i];
    }
    ((short8*)dst)[i] = o;
}

__global__ __launch_bounds__(256) void canon_all_kernel(
    const void* __restrict__ X,
    const void* __restrict__ s0, const void* __restrict__ s1,
    const void* __restrict__ s2, const void* __restrict__ s3,
    short* __restrict__ dX,
    short* __restrict__ d0, short* __restrict__ d1,
    short* __restrict__ d2, short* __restrict__ d3,
    const int* __restrict__ flag)
{
    const int f = *flag;
    const int bid = blockIdx.x;
    if (bid < 6144) {
        canon8(X, dX, bid * 256 + threadIdx.x, f);
    } else {
        const int wb = bid - 6144;
        const int m = wb / 1152;
        const int i = (wb - m * 1152) * 256 + threadIdx.x;
        const void* src = (m == 0) ? s0 : (m == 1) ? s1 : (m == 2) ? s2 : s3;
        short* dst = (m == 0) ? d0 : (m == 1) ? d1 : (m == 2) ? d2 : d3;
        canon8(src, dst, i, f);
    }
}

// ---------------------------------------------------------------------------
// 128x128 NT GEMM, BK=64, dbuf (64KB -> 2 blocks/CU), conflicts 0, ~775 TF.
// L2-band mapping (r16): each XCD owns a fixed 8-row mb band, nb-major walk.
// FETCH 289->117MB measured. Requires 64 mb tiles. mat = nb/12.
// ---------------------------------------------------------------------------
__global__ __launch_bounds__(256) void gemm128_kernel(
    const bf16* __restrict__ A, const bf16* __restrict__ Bw,
    const float* __restrict__ bias,
    bf16* __restrict__ O0, bf16* __restrict__ O1, bf16* __restrict__ O2,
    int K, const int* __restrict__ outFlag)
{
    __shared__ __align__(16) short As[2][128 * 64];
    __shared__ __align__(16) short Bs[2][128 * 64];

    const int tid = threadIdx.x;
    const int lane = tid & 63, w = tid >> 6;
    const int wr = w >> 1, wc = w & 1;
    const int li = lane & 15, lg = lane >> 4;

    const int pp = blockIdx.y * gridDim.x + blockIdx.x;
    const int xcd = pp & 7;
    const int idx = pp >> 3;
    const int mb = xcd * 8 + (idx & 7);
    const int nb = idx >> 3;
    const long mBase = (long)mb * 128;
    const long nGlob = (long)nb * 128;

    const bf16* aSrc[4]; const bf16* bSrc[4]; int ldsOff[4];
#pragma unroll
    for (int u = 0; u < 4; ++u) {
        const int L = u * 4096 + tid * 16;
        const int S = L ^ (((L >> 7) & 7) << 4);
        const int srow = S >> 7;
        const int scol = (S & 127) >> 1;
        aSrc[u] = A + (mBase + srow) * K + scol;
        bSrc[u] = Bw + (nGlob + srow) * K + scol;
        ldsOff[u] = L >> 1;
    }
    const int rxor = (li & 7) << 4;
    int kidx[2];
#pragma unroll
    for (int ks = 0; ks < 2; ++ks)
        kidx[ks] = ((ks * 64 + lg * 16) ^ rxor) >> 1;

    f32x4 acc[4][4] = {};
    const int NT = K >> 6;

    auto stage = [&](int tt, int bb) {
        const long kc = (long)tt * 64;
#pragma unroll
        for (int u = 0; u < 4; ++u)
            __builtin_amdgcn_global_load_lds((GVOID*)(aSrc[u] + kc),
                                             (LVOID*)&As[bb][ldsOff[u]], 16, 0, 0);
#pragma unroll
        for (int u = 0; u < 4; ++u)
            __builtin_amdgcn_global_load_lds((GVOID*)(bSrc[u] + kc),
                                             (LVOID*)&Bs[bb][ldsOff[u]], 16, 0, 0);
    };

    stage(0, 0);
    asm volatile("s_waitcnt vmcnt(0)" ::: "memory");
    __builtin_amdgcn_s_barrier();
    asm volatile("" ::: "memory");

    for (int t = 0; t < NT; ++t) {
        const int cb = t & 1;
        if (t + 1 < NT) stage(t + 1, cb ^ 1);
        const short* Ab = &As[cb][0];
        const short* Bb = &Bs[cb][0];
#pragma unroll
        for (int ks = 0; ks < 2; ++ks) {
            short8 fa[4], fb[4];
#pragma unroll
            for (int m = 0; m < 4; ++m)
                fa[m] = *(const short8*)(Ab + (wr * 64 + m * 16 + li) * 64 + kidx[ks]);
#pragma unroll
            for (int n = 0; n < 4; ++n)
                fb[n] = *(const short8*)(Bb + (wc * 64 + n * 16 + li) * 64 + kidx[ks]);
            __builtin_amdgcn_sched_barrier(0);
            __builtin_amdgcn_s_setprio(1);
#pragma unroll
            for (int m = 0; m < 4; ++m)
#pragma unroll
                for (int n = 0; n < 4; ++n)
                    acc[m][n] = MFMA16(fa[m], fb[n], acc[m][n]);
            __builtin_amdgcn_s_setprio(0);
            __builtin_amdgcn_sched_barrier(0);
        }
        asm volatile("s_waitcnt vmcnt(0)" ::: "memory");
        __builtin_amdgcn_s_barrier();
        asm volatile("" ::: "memory");
    }

    const int f32out = outFlag ? *outFlag : 0;
    const int mat = nb / 12;
    const long colBase = nGlob - (long)mat * 1536;
    bf16* Ob = (mat == 0) ? O0 : (mat == 1) ? O1 : O2;
    if (f32out) {
        float* Cf = (float*)Ob;
#pragma unroll
        for (int n = 0; n < 4; ++n) {
            const long col = colBase + wc * 64 + n * 16 + li;
            const float bv = bias[nGlob + wc * 64 + n * 16 + li];
#pragma unroll
            for (int m = 0; m < 4; ++m) {
                const long row = mBase + wr * 64 + m * 16 + lg * 4;
#pragma unroll
                for (int i = 0; i < 4; ++i)
                    Cf[(row + i) * 1536 + col] = acc[m][n][i] + bv;
            }
        }
    } else {
#pragma unroll
        for (int n = 0; n < 4; ++n) {
            const long col = colBase + wc * 64 + n * 16 + li;
            const float bv = bias[nGlob + wc * 64 + n * 16 + li];
#pragma unroll
            for (int m = 0; m < 4; ++m) {
                const long row = mBase + wr * 64 + m * 16 + lg * 4;
#pragma unroll
                for (int i = 0; i < 4; ++i)
                    Ob[(row + i) * 1536 + col] = __float2bfloat16(acc[m][n][i] + bv);
            }
        }
    }
}

// ---------------------------------------------------------------------------
// Fused per-head RMSNorm + RoPE, in place; y=0 -> Q (qscale), y=1 -> K.
// ---------------------------------------------------------------------------
__global__ __launch_bounds__(256) void norm_rope2_kernel(
    bf16* __restrict__ Qb, bf16* __restrict__ Kb,
    const float* __restrict__ qwc, const float* __restrict__ kwc,
    const float* __restrict__ cosT, const float* __restrict__ sinT,
    float qscale)
{
    bf16* T = blockIdx.y ? Kb : Qb;
    const float* wgt = blockIdx.y ? kwc : qwc;
    const float scale = blockIdx.y ? 1.0f : qscale;

    const int row = blockIdx.x * 256 + threadIdx.x;
    const int tok = row >> 4;
    const int h = row & 15;
    const int spos = tok & 1023;
    bf16* p = T + (size_t)tok * 1536 + h * 96;

    float x[96];
#pragma unroll
    for (int v = 0; v < 12; ++v) {
        short8 t = *(const short8*)(p + v * 8);
#pragma unroll
        for (int j = 0; j < 8; ++j) x[v * 8 + j] = b2f(t[j]);
    }
    float ss = 0.f;
#pragma unroll
    for (int d = 0; d < 96; ++d) ss += x[d] * x[d];
    const float rn = scale / sqrtf(ss * (1.0f / 96.0f) + 1e-6f);

    const float* cr = cosT + spos * 96;
    const float* sr = sinT + spos * 96;

#pragma unroll
    for (int v = 0; v < 12; ++v) {
        short8 o;
#pragma unroll
        for (int j = 0; j < 8; j += 2) {
            const int d = v * 8 + j;
            const float x0 = x[d] * rn * wgt[d];
            const float x1 = x[d + 1] * rn * wgt[d + 1];
            o[j]     = f2b(x0 * cr[d] - x1 * sr[d]);
            o[j + 1] = f2b(x1 * cr[d + 1] + x0 * sr[d + 1]);
        }
        *(short8*)(p + v * 8) = o;
    }
}

// ---------------------------------------------------------------------------
// Flash attention v8 = v7 (permuted-key lane-local P, no Pl LDS) with BOTH
// softmax cross-lane reduces on the VALU pipe: xor-16 via permlane16_swap
// (was ds_bpermute shfl ~120cy on the critical chain) + xor-32 permlane32.
// ---------------------------------------------------------------------------
__global__ __launch_bounds__(512, 2) void attn_kernel(
    const bf16* __restrict__ Q, const bf16* __restrict__ K,
    const bf16* __restrict__ V, bf16* __restrict__ O)
{
    __shared__ __align__(16) short Ks[2][64 * 96];
    __shared__ __align__(16) short Vt[2][96 * 64];

    const int tid = threadIdx.x;
    const int l = tid & 63, w = tid >> 6;
    const int li = l & 15, lg = l >> 4;

    const int p = blockIdx.x;
    const int lb = (p & 7) * 128 + (p >> 3);
    const int qt = lb & 7;
    const int bh = lb >> 3;
    const int b = bh >> 4, h = bh & 15;
    const size_t tokBase = (size_t)b * 1024;

    short8 aq[3];
    {
        const bf16* qp = Q + (tokBase + qt * 128 + w * 16 + li) * 1536 + h * 96;
#pragma unroll
        for (int kk = 0; kk < 3; ++kk)
            aq[kk] = *(const short8*)(qp + kk * 32 + lg * 8);
    }

    float m_r = -1e30f, l_r = 0.f;
    f32x4 o[6] = {};

    const bool kst = (w >= 4);
    int kr[3], km[3], kso[3];
#pragma unroll
    for (int u = 0; u < 3; ++u) {
        const int c = (tid - 256) + 256 * u;
        const int crr = c / 12;
        kr[u] = crr;
        km[u] = (c - crr * 12) * 8;
        kso[u] = (crr * 96 + km[u]) ^ ((crr & 7) << 3);
    }
    const int t2 = tid >> 3;
    const int dh = tid & 7;
    const bf16* vbase = V + (tokBase + 2 * t2) * 1536 + h * 96 + dh * 12;

    // permuted QK fragment rows: row = kt*32 + 4h + 8*(li>>2) + (li&3)
    const int rowbase = ((li >> 2) << 3) + (li & 3);
    const int colb = lg * 8;
    int frow[2][2];
    int fswz[2];
#pragma unroll
    for (int kt = 0; kt < 2; ++kt)
#pragma unroll
        for (int hh = 0; hh < 2; ++hh)
            frow[kt][hh] = (kt * 32 + 4 * hh + rowbase) * 96;
#pragma unroll
    for (int hh = 0; hh < 2; ++hh)
        fswz[hh] = (4 * hh + (li & 3)) << 3;

    const int vswz = ((li >> 1) & 7) << 3;

    short8 kreg[3];
    short4v vr0[3], vr1[3];
    auto loadT = [&](int tt) {
        if (kst) {
#pragma unroll
            for (int u = 0; u < 3; ++u)
                kreg[u] = *(const short8*)(K + (tokBase + tt + kr[u]) * 1536 + h * 96 + km[u]);
        } else {
            const bf16* vp = vbase + (size_t)tt * 1536;
#pragma unroll
            for (int u = 0; u < 3; ++u) {
                vr0[u] = *(const short4v*)(vp + u * 4);
                vr1[u] = *(const short4v*)(vp + 1536 + u * 4);
            }
        }
    };
    auto writeT = [&](int bb) {
        if (kst) {
#pragma unroll
            for (int u = 0; u < 3; ++u)
                *(short8*)&Ks[bb][kso[u]] = kreg[u];
        } else {
            unsigned* Vt32 = (unsigned*)&Vt[bb][0];
#pragma unroll
            for (int u = 0; u < 3; ++u)
#pragma unroll
                for (int j = 0; j < 4; ++j) {
                    const int d = dh * 12 + u * 4 + j;
                    const unsigned pk = ((unsigned)(unsigned short)vr0[u][j]) |
                                        (((unsigned)(unsigned short)vr1[u][j]) << 16);
                    Vt32[(d * 32 + t2) ^ (((d >> 1) & 7) << 2)] = pk;
                }
        }
    };

    loadT(0);
    writeT(0);
    loadT(64);
    __syncthreads();

    for (int t = 0; t < 16; ++t) {
        const int cb = t & 1;

        f32x4 s4[4] = {};
#pragma unroll
        for (int kk = 0; kk < 3; ++kk) {
            const int ck = kk * 32 + colb;
#pragma unroll
            for (int kt = 0; kt < 2; ++kt)
#pragma unroll
                for (int hh = 0; hh < 2; ++hh) {
                    short8 fk = *(const short8*)&Ks[cb][(frow[kt][hh] + ck) ^ fswz[hh]];
                    s4[kt * 2 + hh] = MFMA16(fk, aq[kk], s4[kt * 2 + hh]);
                }
        }

        if (t < 15) writeT(cb ^ 1);
        if (t < 14) loadT((t + 2) * 64);

        unsigned pdw[4][2];
        {
            float mk[4];
#pragma unroll
            for (int kn = 0; kn < 4; ++kn)
                mk[kn] = fmaxf(fmaxf(s4[kn][0], s4[kn][1]),
                               fmaxf(s4[kn][2], s4[kn][3]));
            float pm = fmaxf(fmaxf(mk[0], mk[1]), fmaxf(mk[2], mk[3]));
            pm = maxx16(pm);
            pm = maxx32(pm);

            float alpha = 1.0f;
            const bool need = (pm > m_r + 8.0f);
            if (need) { alpha = exp2f(m_r - pm); m_r = pm; }
            const float mn = m_r;

            float rs = 0.f;
#pragma unroll
            for (int kn = 0; kn < 4; ++kn) {
                float p0 = exp2f(s4[kn][0] - mn);
                float p1 = exp2f(s4[kn][1] - mn);
                float p2 = exp2f(s4[kn][2] - mn);
                float p3 = exp2f(s4[kn][3] - mn);
                rs += (p0 + p1) + (p2 + p3);
                pdw[kn][0] = packbf2(p0, p1);
                pdw[kn][1] = packbf2(p2, p3);
            }
            rs = addx16(rs);
            rs = addx32(rs);
            l_r = l_r * alpha + rs;
            if (need) {
#pragma unroll
                for (int dn = 0; dn < 6; ++dn)
#pragma unroll
                    for (int i = 0; i < 4; ++i) o[dn][i] *= alpha;
            }
        }

#pragma unroll
        for (int kt = 0; kt < 2; ++kt) {
            union { unsigned u[4]; short8 s; } pa;
            pa.u[0] = pdw[kt * 2][0];
            pa.u[1] = pdw[kt * 2][1];
            pa.u[2] = pdw[kt * 2 + 1][0];
            pa.u[3] = pdw[kt * 2 + 1][1];
#pragma unroll
            for (int dn = 0; dn < 6; ++dn) {
                short8 fv = *(const short8*)&Vt[cb][((dn * 16 + li) * 64 + kt * 32 + lg * 8) ^ vswz];
                o[dn] = MFMA16(fv, pa.s, o[dn]);
            }
        }

        __syncthreads();
    }

    {
        const float inv = 1.0f / l_r;
        const size_t row = tokBase + qt * 128 + w * 16 + li;
#pragma unroll
        for (int dn = 0; dn < 6; ++dn) {
            short4v ov;
#pragma unroll
            for (int i = 0; i < 4; ++i) ov[i] = bf2s(o[dn][i] * inv);
            *(short4v*)&O[row * 1536 + h * 96 + dn * 16 + lg * 4] = ov;
        }
    }
}

// ---------------------------------------------------------------------------
extern "C" void kernel_launch(void* const* d_in, const int* in_sizes, int n_in,
                              void* d_out, int out_size, void* d_ws, size_t ws_size,
                              hipStream_t stream) {
    const void* X  = d_in[0];
    const void* Wq = d_in[1];
    const void* bq = d_in[2];
    const void* Wk = d_in[3];
    const void* bk = d_in[4];
    const void* Wv = d_in[5];
    const void* bv = d_in[6];
    const void* qw = d_in[7];
    const void* kw = d_in[8];
    const void* Wo = d_in[9];
    const void* bo = d_in[10];

    char* ws = (char*)d_ws;
    size_t off = 0;
    int* flag = (int*)ws;                      off += 256;
    float* cosT = (float*)(ws + off);          off += 1024 * 96 * 4;
    float* sinT = (float*)(ws + off);          off += 1024 * 96 * 4;
    float* biasqkv = (float*)(ws + off);       off += 4608 * 4;
    float* boc  = (float*)(ws + off);          off += 1536 * 4;
    float* qwc  = (float*)(ws + off);          off += 128 * 4;
    float* kwc  = (float*)(ws + off);          off += 128 * 4;
    off = (off + 255) & ~(size_t)255;
    bf16* Wc  = (bf16*)(ws + off);             off += (size_t)4608 * 1536 * 2;
    bf16* Woc = (bf16*)(ws + off);             off += (size_t)1536 * 1536 * 2;
    bf16* Xc  = (bf16*)(ws + off);             off += (size_t)8192 * 1536 * 2;  // reused as AO
    bf16* Qb  = (bf16*)(ws + off);             off += (size_t)8192 * 1536 * 2;
    bf16* Kb  = (bf16*)(ws + off);             off += (size_t)8192 * 1536 * 2;
    bf16* Vb  = (bf16*)(ws + off);             off += (size_t)8192 * 1536 * 2;
    bf16* AO  = Xc;

    prep_kernel<<<385, 256, 0, stream>>>((const unsigned*)X, bq, bk, bv, bo, qw, kw,
                                         flag, biasqkv, boc, qwc, kwc, cosT, sinT);

    canon_all_kernel<<<10752, 256, 0, stream>>>(
        X, Wq, Wk, Wv, Wo,
        (short*)Xc, (short*)Wc, (short*)(Wc + (size_t)1536 * 1536),
        (short*)(Wc + (size_t)2 * 1536 * 1536), (short*)Woc, flag);

    // fused QKV projection: [8192,4608] = Xc @ Wc^T + biasqkv -> Qb|Kb|Vb
    gemm128_kernel<<<dim3(36, 64), 256, 0, stream>>>(
        Xc, Wc, biasqkv, Qb, Kb, Vb, 1536, nullptr);

    const float qscale = (float)(0.10206207261596577 * 1.4426950408889634);
    norm_rope2_kernel<<<dim3(512, 2), 256, 0, stream>>>(Qb, Kb, qwc, kwc, cosT, sinT, qscale);

    attn_kernel<<<1024, 512, 0, stream>>>(Qb, Kb, Vb, AO);

    gemm128_kernel<<<dim3(12, 64), 256, 0, stream>>>(
        AO, Woc, boc, (bf16*)d_out, (bf16*)d_out, (bf16*)d_out, 1536, flag);
}